// Round 4
// baseline (232.832 us; speedup 1.0000x reference)
//
#include <hip/hip_runtime.h>
#include <hip/hip_bf16.h>

// MoE FFN: T=4096 tokens, D=1024, E=8, H=1408, top-2.
// R4: GEMMs get (a) 2-phase double-buffered pipeline (stage next tile before
// computing current, one barrier per K-step), (b) expert->XCD block mapping
// with mt-fastest order for L2 locality (A rows stay resident per XCD).

#define T_TOK 4096
#define D_DIM 1024
#define E_NUM 8
#define H_DIM 1408

typedef __bf16 bf16_t;
typedef __bf16 bf16x8 __attribute__((ext_vector_type(8)));
typedef float f32x4 __attribute__((ext_vector_type(4)));

// ---- workspace layout (bytes) ----
#define OFF_COUNTS   0
#define OFF_COMB     256                                   // T*E*4 = 131072
#define OFF_LISTS    (OFF_COMB + T_TOK*E_NUM*4)            // E*T*4 = 131072
#define OFF_PAIRS    (OFF_LISTS + E_NUM*T_TOK*4)           // T bytes
#define OFF_XBF      (OFF_PAIRS + T_TOK)                   // T*D*2
#define OFF_WGT      (OFF_XBF + (size_t)T_TOK*D_DIM*2)     // E*H*D*2 each
#define OFF_WUT      (OFF_WGT + (size_t)E_NUM*H_DIM*D_DIM*2)
#define OFF_WDT      (OFF_WUT + (size_t)E_NUM*H_DIM*D_DIM*2)
#define OFF_H        (OFF_WDT + (size_t)E_NUM*H_DIM*D_DIM*2)
#define OFF_CONTRIB  (OFF_H + (size_t)2*T_TOK*H_DIM*2)
// total ~117.7 MB

__device__ __forceinline__ void gload16(const bf16_t* g, bf16_t* l) {
    __builtin_amdgcn_global_load_lds(
        (const __attribute__((address_space(1))) void*)g,
        (__attribute__((address_space(3))) void*)l,
        16, 0, 0);
}

// Tiled transpose+convert: per expert, in [R][C] fp32 -> out [C][R] bf16.
__global__ __launch_bounds__(256) void transpose_cvt_kernel(
    const float* __restrict__ in, bf16_t* __restrict__ out, int R, int C)
{
    int e = blockIdx.z;
    int rt = blockIdx.y, ct = blockIdx.x;
    __shared__ bf16_t tile[64][65];
    int tid = threadIdx.x;
    int r = tid >> 2, c0 = (tid & 3) * 16;
    const float* src = in + ((size_t)e * R + rt * 64) * C + (size_t)ct * 64;
#pragma unroll
    for (int q = 0; q < 4; ++q) {
        float4 f = *(const float4*)(src + (size_t)r * C + c0 + q * 4);
        tile[c0 + q * 4 + 0][r] = (bf16_t)f.x;
        tile[c0 + q * 4 + 1][r] = (bf16_t)f.y;
        tile[c0 + q * 4 + 2][r] = (bf16_t)f.z;
        tile[c0 + q * 4 + 3][r] = (bf16_t)f.w;
    }
    __syncthreads();
    bf16_t* dst = out + ((size_t)e * C + ct * 64) * R + (size_t)rt * 64;
    int cc = tid >> 2, rr0 = (tid & 3) * 16;
    bf16x8 v0, v1;
#pragma unroll
    for (int q = 0; q < 8; ++q) { v0[q] = tile[cc][rr0 + q]; v1[q] = tile[cc][rr0 + 8 + q]; }
    *(bf16x8*)(dst + (size_t)cc * R + rr0) = v0;
    *(bf16x8*)(dst + (size_t)cc * R + rr0 + 8) = v1;
}

// Router phase A: 4 waves/block, one token per wave. No atomics. x -> bf16.
__global__ __launch_bounds__(256) void router_score_kernel(
    const float* __restrict__ x, const float* __restrict__ wr,
    bf16_t* __restrict__ xbf, float* __restrict__ comb,
    unsigned char* __restrict__ pairs)
{
    int widx = threadIdx.x >> 6;
    int lane = threadIdx.x & 63;
    int t = blockIdx.x * 4 + widx;
    const float* xr = x + (size_t)t * D_DIM;

    {
        const float4* xv4 = (const float4*)(xr + lane * 16);
        bf16_t* xbr = xbf + (size_t)t * D_DIM + lane * 16;
        float4 f0 = xv4[0], f1 = xv4[1], f2 = xv4[2], f3 = xv4[3];
        bf16x8 v0, v1;
        v0[0] = (bf16_t)f0.x; v0[1] = (bf16_t)f0.y; v0[2] = (bf16_t)f0.z; v0[3] = (bf16_t)f0.w;
        v0[4] = (bf16_t)f1.x; v0[5] = (bf16_t)f1.y; v0[6] = (bf16_t)f1.z; v0[7] = (bf16_t)f1.w;
        v1[0] = (bf16_t)f2.x; v1[1] = (bf16_t)f2.y; v1[2] = (bf16_t)f2.z; v1[3] = (bf16_t)f2.w;
        v1[4] = (bf16_t)f3.x; v1[5] = (bf16_t)f3.y; v1[6] = (bf16_t)f3.z; v1[7] = (bf16_t)f3.w;
        *(bf16x8*)(xbr) = v0;
        *(bf16x8*)(xbr + 8) = v1;
    }

    float acc[E_NUM] = {0.f, 0.f, 0.f, 0.f, 0.f, 0.f, 0.f, 0.f};
#pragma unroll
    for (int j = 0; j < D_DIM / 64; ++j) {
        float xv = xr[lane + 64 * j];
        const float* w = wr + (size_t)(lane + 64 * j) * E_NUM;
#pragma unroll
        for (int e = 0; e < E_NUM; ++e) acc[e] += xv * w[e];
    }
#pragma unroll
    for (int off = 32; off > 0; off >>= 1) {
#pragma unroll
        for (int e = 0; e < E_NUM; ++e) acc[e] += __shfl_xor(acc[e], off, 64);
    }
    if (lane == 0) {
        float m = acc[0];
#pragma unroll
        for (int e = 1; e < E_NUM; ++e) m = fmaxf(m, acc[e]);
        float ex[E_NUM], Z = 0.f;
#pragma unroll
        for (int e = 0; e < E_NUM; ++e) { ex[e] = expf(acc[e] - m); Z += ex[e]; }
        float inv = 1.f / Z;
        int e0 = 0; float v0 = ex[0];
#pragma unroll
        for (int e = 1; e < E_NUM; ++e) if (ex[e] > v0) { v0 = ex[e]; e0 = e; }
        int e1 = -1; float v1 = -1.f;
#pragma unroll
        for (int e = 0; e < E_NUM; ++e) if (e != e0 && ex[e] > v1) { v1 = ex[e]; e1 = e; }
        float p0 = v0 * inv, p1 = v1 * inv;
        float s = p0 + p1 + 1e-20f;
        comb[t * E_NUM + e0] = p0 / s;
        comb[t * E_NUM + e1] = p1 / s;
        pairs[t] = (unsigned char)(e0 | (e1 << 4));
    }
}

// Router phase B: one block per expert, LDS-scan compaction. Deterministic.
__global__ __launch_bounds__(256) void build_lists_kernel(
    const unsigned char* __restrict__ pairs, int* __restrict__ lists,
    int* __restrict__ counts)
{
    int e = blockIdx.x;
    int tid = threadIdx.x;
    __shared__ int cnt[256];

    const int TPT = T_TOK / 256;
    int n = 0;
#pragma unroll
    for (int q = 0; q < TPT; ++q) {
        int p = pairs[tid * TPT + q];
        if ((p & 15) == e || (p >> 4) == e) ++n;
    }
    cnt[tid] = n;
    __syncthreads();
#pragma unroll
    for (int off = 1; off < 256; off <<= 1) {
        int v = (tid >= off) ? cnt[tid - off] : 0;
        __syncthreads();
        cnt[tid] += v;
        __syncthreads();
    }
    int base = cnt[tid] - n;
    if (tid == 255) counts[e] = cnt[255];
    int* dst = lists + e * T_TOK;
#pragma unroll
    for (int q = 0; q < TPT; ++q) {
        int t = tid * TPT + q;
        int p = pairs[t];
        if ((p & 15) == e)      dst[base++] = 2 * t;
        else if ((p >> 4) == e) dst[base++] = 2 * t + 1;
    }
}

// GEMM1: h[slot] = silu(x@Wg)*(x@Wu). 128x128 tile, BK=32, 2-phase dbuf.
// Block mapping: expert = bid&7 (-> one XCD per expert), mt fastest.
__global__ __launch_bounds__(256, 2) void gemm1_kernel(
    const bf16_t* __restrict__ xbf, const bf16_t* __restrict__ wgT,
    const bf16_t* __restrict__ wuT, const int* __restrict__ lists,
    const int* __restrict__ counts, bf16_t* __restrict__ h)
{
    const int MT = T_TOK / 128;  // 32
    int bid = blockIdx.x;
    int e = bid & 7;
    int within = bid >> 3;       // 0..351
    int nt = within / MT;        // 0..10
    int mt = within - nt * MT;   // mt fastest: A rows of expert stay in L2
    int cnt = counts[e];
    int mbase = mt * 128;
    if (mbase >= cnt) return;
    int rows = min(128, cnt - mbase);

    __shared__ __align__(16) bf16_t As[2][128 * 32];
    __shared__ __align__(16) bf16_t Bg[2][128 * 32];
    __shared__ __align__(16) bf16_t Bu[2][128 * 32];
    __shared__ int slots[128];

    int tid = threadIdx.x;
    if (tid < 128) slots[tid] = (tid < rows) ? lists[e * T_TOK + mbase + tid] : 0;
    __syncthreads();

    int r0 = tid >> 2;
    int c0 = (tid & 3) * 8;
    const bf16_t* gA0 = xbf + (size_t)(slots[r0] >> 1) * D_DIM + c0;
    const bf16_t* gA1 = xbf + (size_t)(slots[64 + r0] >> 1) * D_DIM + c0;
    const bf16_t* gB0 = wgT + ((size_t)e * H_DIM + nt * 128 + r0) * D_DIM + c0;
    const bf16_t* gB1 = gB0 + (size_t)64 * D_DIM;
    const bf16_t* gU0 = wuT + ((size_t)e * H_DIM + nt * 128 + r0) * D_DIM + c0;
    const bf16_t* gU1 = gU0 + (size_t)64 * D_DIM;

    int wid = tid >> 6, lane = tid & 63;
    int wm = (wid >> 1) * 64, wn = (wid & 1) * 64;
    int lr = lane & 15, lq = lane >> 4;

    f32x4 accg[4][4], accu[4][4];
#pragma unroll
    for (int i = 0; i < 4; ++i)
#pragma unroll
        for (int j = 0; j < 4; ++j) {
            accg[i][j] = (f32x4){0.f, 0.f, 0.f, 0.f};
            accu[i][j] = (f32x4){0.f, 0.f, 0.f, 0.f};
        }

    // prologue: stage k-tile 0 into buffer 0
    {
        bf16_t* lA = As[0] + tid * 8;
        bf16_t* lG = Bg[0] + tid * 8;
        bf16_t* lU = Bu[0] + tid * 8;
        gload16(gA0, lA); gload16(gA1, lA + 2048);
        gload16(gB0, lG); gload16(gB1, lG + 2048);
        gload16(gU0, lU); gload16(gU1, lU + 2048);
    }
    __syncthreads();

    int cur = 0;
    for (int kt = 0; kt < D_DIM / 32; ++kt) {
        // stage NEXT k-tile into the other buffer (loads in flight over MFMA)
        if (kt + 1 < D_DIM / 32) {
            int nxt = cur ^ 1;
            int ko = (kt + 1) * 32;
            bf16_t* lA = As[nxt] + tid * 8;
            bf16_t* lG = Bg[nxt] + tid * 8;
            bf16_t* lU = Bu[nxt] + tid * 8;
            gload16(gA0 + ko, lA); gload16(gA1 + ko, lA + 2048);
            gload16(gB0 + ko, lG); gload16(gB1 + ko, lG + 2048);
            gload16(gU0 + ko, lU); gload16(gU1 + ko, lU + 2048);
        }
        // compute CURRENT buffer
        bf16x8 af[4], bg[4], bu[4];
#pragma unroll
        for (int i = 0; i < 4; ++i)
            af[i] = *(const bf16x8*)(As[cur] + (wm + i * 16 + lr) * 32 + lq * 8);
#pragma unroll
        for (int j = 0; j < 4; ++j) {
            bg[j] = *(const bf16x8*)(Bg[cur] + (wn + j * 16 + lr) * 32 + lq * 8);
            bu[j] = *(const bf16x8*)(Bu[cur] + (wn + j * 16 + lr) * 32 + lq * 8);
        }
#pragma unroll
        for (int i = 0; i < 4; ++i)
#pragma unroll
            for (int j = 0; j < 4; ++j) {
                accg[i][j] = __builtin_amdgcn_mfma_f32_16x16x32_bf16(af[i], bg[j], accg[i][j], 0, 0, 0);
                accu[i][j] = __builtin_amdgcn_mfma_f32_16x16x32_bf16(af[i], bu[j], accu[i][j], 0, 0, 0);
            }
        // vmcnt(0)+lgkmcnt(0)+barrier: next tile landed during compute
        __syncthreads();
        cur ^= 1;
    }

#pragma unroll
    for (int i = 0; i < 4; ++i) {
#pragma unroll
        for (int jj = 0; jj < 4; ++jj) {
            int row = wm + i * 16 + lq * 4 + jj;
            if (row < rows) {
                int slot = slots[row];
                bf16_t* hrow = h + (size_t)slot * H_DIM + (size_t)nt * 128 + wn;
#pragma unroll
                for (int j = 0; j < 4; ++j) {
                    float g = accg[i][j][jj];
                    float u = accu[i][j][jj];
                    float val = (g / (1.f + __expf(-g))) * u;
                    hrow[j * 16 + lr] = (bf16_t)val;
                }
            }
        }
    }
}

// GEMM2: contrib[slot] = (h[slot] @ Wd[e]) * comb_weight. 2-phase dbuf.
__global__ __launch_bounds__(256, 2) void gemm2_kernel(
    const bf16_t* __restrict__ h, const bf16_t* __restrict__ wdT,
    const int* __restrict__ lists, const int* __restrict__ counts,
    const float* __restrict__ comb, bf16_t* __restrict__ contrib)
{
    const int MT = T_TOK / 128;  // 32
    int bid = blockIdx.x;
    int e = bid & 7;
    int within = bid >> 3;       // 0..255
    int nt = within / MT;        // 0..7
    int mt = within - nt * MT;
    int cnt = counts[e];
    int mbase = mt * 128;
    if (mbase >= cnt) return;
    int rows = min(128, cnt - mbase);

    __shared__ __align__(16) bf16_t As[2][128 * 32];
    __shared__ __align__(16) bf16_t Bs[2][128 * 32];
    __shared__ int slots[128];

    int tid = threadIdx.x;
    if (tid < 128) slots[tid] = (tid < rows) ? lists[e * T_TOK + mbase + tid] : 0;
    __syncthreads();

    int r0 = tid >> 2;
    int c0 = (tid & 3) * 8;
    const bf16_t* gA0 = h + (size_t)slots[r0] * H_DIM + c0;
    const bf16_t* gA1 = h + (size_t)slots[64 + r0] * H_DIM + c0;
    const bf16_t* gB0 = wdT + ((size_t)e * D_DIM + nt * 128 + r0) * H_DIM + c0;
    const bf16_t* gB1 = gB0 + (size_t)64 * H_DIM;

    int wid = tid >> 6, lane = tid & 63;
    int wm = (wid >> 1) * 64, wn = (wid & 1) * 64;
    int lr = lane & 15, lq = lane >> 4;

    f32x4 acc[4][4];
#pragma unroll
    for (int i = 0; i < 4; ++i)
#pragma unroll
        for (int j = 0; j < 4; ++j) acc[i][j] = (f32x4){0.f, 0.f, 0.f, 0.f};

    {
        bf16_t* lA = As[0] + tid * 8;
        bf16_t* lB = Bs[0] + tid * 8;
        gload16(gA0, lA); gload16(gA1, lA + 2048);
        gload16(gB0, lB); gload16(gB1, lB + 2048);
    }
    __syncthreads();

    int cur = 0;
    for (int kt = 0; kt < H_DIM / 32; ++kt) {
        if (kt + 1 < H_DIM / 32) {
            int nxt = cur ^ 1;
            int ko = (kt + 1) * 32;
            bf16_t* lA = As[nxt] + tid * 8;
            bf16_t* lB = Bs[nxt] + tid * 8;
            gload16(gA0 + ko, lA); gload16(gA1 + ko, lA + 2048);
            gload16(gB0 + ko, lB); gload16(gB1 + ko, lB + 2048);
        }
        bf16x8 af[4], bf[4];
#pragma unroll
        for (int i = 0; i < 4; ++i)
            af[i] = *(const bf16x8*)(As[cur] + (wm + i * 16 + lr) * 32 + lq * 8);
#pragma unroll
        for (int j = 0; j < 4; ++j)
            bf[j] = *(const bf16x8*)(Bs[cur] + (wn + j * 16 + lr) * 32 + lq * 8);
#pragma unroll
        for (int i = 0; i < 4; ++i)
#pragma unroll
            for (int j = 0; j < 4; ++j)
                acc[i][j] = __builtin_amdgcn_mfma_f32_16x16x32_bf16(af[i], bf[j], acc[i][j], 0, 0, 0);
        __syncthreads();
        cur ^= 1;
    }

#pragma unroll
    for (int i = 0; i < 4; ++i) {
#pragma unroll
        for (int jj = 0; jj < 4; ++jj) {
            int row = wm + i * 16 + lq * 4 + jj;
            if (row < rows) {
                int slot = slots[row];
                float wgt = comb[(slot >> 1) * E_NUM + e];
                bf16_t* crow = contrib + (size_t)slot * D_DIM + (size_t)nt * 128 + wn;
#pragma unroll
                for (int j = 0; j < 4; ++j)
                    crow[j * 16 + lr] = (bf16_t)(acc[i][j][jj] * wgt);
            }
        }
    }
}

// out[t][d] = contrib[2t][d] + contrib[2t+1][d]
__global__ __launch_bounds__(256) void combine_kernel(
    const bf16_t* __restrict__ contrib, float* __restrict__ out)
{
    int idx = blockIdx.x * 256 + threadIdx.x;
    int t = idx >> 7;
    int d = (idx & 127) * 8;
    bf16x8 a = *(const bf16x8*)(contrib + (size_t)(2 * t) * D_DIM + d);
    bf16x8 b = *(const bf16x8*)(contrib + (size_t)(2 * t + 1) * D_DIM + d);
    float4 r0, r1;
    r0.x = (float)a[0] + (float)b[0];
    r0.y = (float)a[1] + (float)b[1];
    r0.z = (float)a[2] + (float)b[2];
    r0.w = (float)a[3] + (float)b[3];
    r1.x = (float)a[4] + (float)b[4];
    r1.y = (float)a[5] + (float)b[5];
    r1.z = (float)a[6] + (float)b[6];
    r1.w = (float)a[7] + (float)b[7];
    *(float4*)(out + (size_t)t * D_DIM + d) = r0;
    *(float4*)(out + (size_t)t * D_DIM + d + 4) = r1;
}

extern "C" void kernel_launch(void* const* d_in, const int* in_sizes, int n_in,
                              void* d_out, int out_size, void* d_ws, size_t ws_size,
                              hipStream_t stream)
{
    const float* x  = (const float*)d_in[0];
    const float* wr = (const float*)d_in[1];
    const float* wg = (const float*)d_in[2];
    const float* wu = (const float*)d_in[3];
    const float* wd = (const float*)d_in[4];
    float* out = (float*)d_out;

    char* ws = (char*)d_ws;
    int*    counts  = (int*)(ws + OFF_COUNTS);
    float*  comb    = (float*)(ws + OFF_COMB);
    int*    lists   = (int*)(ws + OFF_LISTS);
    unsigned char* pairs = (unsigned char*)(ws + OFF_PAIRS);
    bf16_t* xbf     = (bf16_t*)(ws + OFF_XBF);
    bf16_t* wgT     = (bf16_t*)(ws + OFF_WGT);
    bf16_t* wuT     = (bf16_t*)(ws + OFF_WUT);
    bf16_t* wdT     = (bf16_t*)(ws + OFF_WDT);
    bf16_t* h       = (bf16_t*)(ws + OFF_H);
    bf16_t* contrib = (bf16_t*)(ws + OFF_CONTRIB);

    // wg, wu: [E][D][H] -> [E][H][D] bf16
    transpose_cvt_kernel<<<dim3(H_DIM / 64, D_DIM / 64, E_NUM), dim3(256), 0, stream>>>(
        wg, wgT, D_DIM, H_DIM);
    transpose_cvt_kernel<<<dim3(H_DIM / 64, D_DIM / 64, E_NUM), dim3(256), 0, stream>>>(
        wu, wuT, D_DIM, H_DIM);
    // wd: [E][H][D] -> [E][D][H] bf16
    transpose_cvt_kernel<<<dim3(D_DIM / 64, H_DIM / 64, E_NUM), dim3(256), 0, stream>>>(
        wd, wdT, H_DIM, D_DIM);
    router_score_kernel<<<dim3(T_TOK / 4), dim3(256), 0, stream>>>(
        x, wr, xbf, comb, pairs);
    build_lists_kernel<<<dim3(E_NUM), dim3(256), 0, stream>>>(pairs, lists, counts);
    gemm1_kernel<<<dim3(E_NUM * (T_TOK / 128) * (H_DIM / 128)), dim3(256), 0, stream>>>(
        xbf, wgT, wuT, lists, counts, h);
    gemm2_kernel<<<dim3(E_NUM * (T_TOK / 128) * (D_DIM / 128)), dim3(256), 0, stream>>>(
        h, wdT, lists, counts, comb, contrib);
    combine_kernel<<<dim3(T_TOK * D_DIM / 8 / 256), dim3(256), 0, stream>>>(contrib, out);
}

// Round 5
// 207.166 us; speedup vs baseline: 1.1239x; 1.1239x over previous
//
#include <hip/hip_runtime.h>
#include <hip/hip_bf16.h>

// MoE FFN: T=4096 tokens, D=1024, E=8, H=1408, top-2.
// R5: GEMM K-loops use counted-vmcnt pipelining (T4): stage(k+1) issued, then
// s_waitcnt vmcnt(6) [only tile-k's loads] + s_barrier before compute, and a
// trailing s_barrier protecting buffer reuse. Next-tile loads stay in flight
// across the whole compute window (no full drain). XCD expert mapping kept.

#define T_TOK 4096
#define D_DIM 1024
#define E_NUM 8
#define H_DIM 1408

typedef __bf16 bf16_t;
typedef __bf16 bf16x8 __attribute__((ext_vector_type(8)));
typedef float f32x4 __attribute__((ext_vector_type(4)));

// ---- workspace layout (bytes) ----
#define OFF_COUNTS   0
#define OFF_COMB     256                                   // T*E*4 = 131072
#define OFF_LISTS    (OFF_COMB + T_TOK*E_NUM*4)            // E*T*4 = 131072
#define OFF_PAIRS    (OFF_LISTS + E_NUM*T_TOK*4)           // T bytes
#define OFF_XBF      (OFF_PAIRS + T_TOK)                   // T*D*2
#define OFF_WGT      (OFF_XBF + (size_t)T_TOK*D_DIM*2)     // E*H*D*2 each
#define OFF_WUT      (OFF_WGT + (size_t)E_NUM*H_DIM*D_DIM*2)
#define OFF_WDT      (OFF_WUT + (size_t)E_NUM*H_DIM*D_DIM*2)
#define OFF_H        (OFF_WDT + (size_t)E_NUM*H_DIM*D_DIM*2)
#define OFF_CONTRIB  (OFF_H + (size_t)2*T_TOK*H_DIM*2)
// total ~117.7 MB

__device__ __forceinline__ void gload16(const bf16_t* g, bf16_t* l) {
    __builtin_amdgcn_global_load_lds(
        (const __attribute__((address_space(1))) void*)g,
        (__attribute__((address_space(3))) void*)l,
        16, 0, 0);
}

// Tiled transpose+convert: per expert, in [R][C] fp32 -> out [C][R] bf16.
__global__ __launch_bounds__(256) void transpose_cvt_kernel(
    const float* __restrict__ in, bf16_t* __restrict__ out, int R, int C)
{
    int e = blockIdx.z;
    int rt = blockIdx.y, ct = blockIdx.x;
    __shared__ bf16_t tile[64][65];
    int tid = threadIdx.x;
    int r = tid >> 2, c0 = (tid & 3) * 16;
    const float* src = in + ((size_t)e * R + rt * 64) * C + (size_t)ct * 64;
#pragma unroll
    for (int q = 0; q < 4; ++q) {
        float4 f = *(const float4*)(src + (size_t)r * C + c0 + q * 4);
        tile[c0 + q * 4 + 0][r] = (bf16_t)f.x;
        tile[c0 + q * 4 + 1][r] = (bf16_t)f.y;
        tile[c0 + q * 4 + 2][r] = (bf16_t)f.z;
        tile[c0 + q * 4 + 3][r] = (bf16_t)f.w;
    }
    __syncthreads();
    bf16_t* dst = out + ((size_t)e * C + ct * 64) * R + (size_t)rt * 64;
    int cc = tid >> 2, rr0 = (tid & 3) * 16;
    bf16x8 v0, v1;
#pragma unroll
    for (int q = 0; q < 8; ++q) { v0[q] = tile[cc][rr0 + q]; v1[q] = tile[cc][rr0 + 8 + q]; }
    *(bf16x8*)(dst + (size_t)cc * R + rr0) = v0;
    *(bf16x8*)(dst + (size_t)cc * R + rr0 + 8) = v1;
}

// Router phase A: 4 waves/block, one token per wave. No atomics. x -> bf16.
__global__ __launch_bounds__(256) void router_score_kernel(
    const float* __restrict__ x, const float* __restrict__ wr,
    bf16_t* __restrict__ xbf, float* __restrict__ comb,
    unsigned char* __restrict__ pairs)
{
    int widx = threadIdx.x >> 6;
    int lane = threadIdx.x & 63;
    int t = blockIdx.x * 4 + widx;
    const float* xr = x + (size_t)t * D_DIM;

    {
        const float4* xv4 = (const float4*)(xr + lane * 16);
        bf16_t* xbr = xbf + (size_t)t * D_DIM + lane * 16;
        float4 f0 = xv4[0], f1 = xv4[1], f2 = xv4[2], f3 = xv4[3];
        bf16x8 v0, v1;
        v0[0] = (bf16_t)f0.x; v0[1] = (bf16_t)f0.y; v0[2] = (bf16_t)f0.z; v0[3] = (bf16_t)f0.w;
        v0[4] = (bf16_t)f1.x; v0[5] = (bf16_t)f1.y; v0[6] = (bf16_t)f1.z; v0[7] = (bf16_t)f1.w;
        v1[0] = (bf16_t)f2.x; v1[1] = (bf16_t)f2.y; v1[2] = (bf16_t)f2.z; v1[3] = (bf16_t)f2.w;
        v1[4] = (bf16_t)f3.x; v1[5] = (bf16_t)f3.y; v1[6] = (bf16_t)f3.z; v1[7] = (bf16_t)f3.w;
        *(bf16x8*)(xbr) = v0;
        *(bf16x8*)(xbr + 8) = v1;
    }

    float acc[E_NUM] = {0.f, 0.f, 0.f, 0.f, 0.f, 0.f, 0.f, 0.f};
#pragma unroll
    for (int j = 0; j < D_DIM / 64; ++j) {
        float xv = xr[lane + 64 * j];
        const float* w = wr + (size_t)(lane + 64 * j) * E_NUM;
#pragma unroll
        for (int e = 0; e < E_NUM; ++e) acc[e] += xv * w[e];
    }
#pragma unroll
    for (int off = 32; off > 0; off >>= 1) {
#pragma unroll
        for (int e = 0; e < E_NUM; ++e) acc[e] += __shfl_xor(acc[e], off, 64);
    }
    if (lane == 0) {
        float m = acc[0];
#pragma unroll
        for (int e = 1; e < E_NUM; ++e) m = fmaxf(m, acc[e]);
        float ex[E_NUM], Z = 0.f;
#pragma unroll
        for (int e = 0; e < E_NUM; ++e) { ex[e] = expf(acc[e] - m); Z += ex[e]; }
        float inv = 1.f / Z;
        int e0 = 0; float v0 = ex[0];
#pragma unroll
        for (int e = 1; e < E_NUM; ++e) if (ex[e] > v0) { v0 = ex[e]; e0 = e; }
        int e1 = -1; float v1 = -1.f;
#pragma unroll
        for (int e = 0; e < E_NUM; ++e) if (e != e0 && ex[e] > v1) { v1 = ex[e]; e1 = e; }
        float p0 = v0 * inv, p1 = v1 * inv;
        float s = p0 + p1 + 1e-20f;
        comb[t * E_NUM + e0] = p0 / s;
        comb[t * E_NUM + e1] = p1 / s;
        pairs[t] = (unsigned char)(e0 | (e1 << 4));
    }
}

// Router phase B: one block per expert, LDS-scan compaction. Deterministic.
__global__ __launch_bounds__(256) void build_lists_kernel(
    const unsigned char* __restrict__ pairs, int* __restrict__ lists,
    int* __restrict__ counts)
{
    int e = blockIdx.x;
    int tid = threadIdx.x;
    __shared__ int cnt[256];

    const int TPT = T_TOK / 256;
    int n = 0;
#pragma unroll
    for (int q = 0; q < TPT; ++q) {
        int p = pairs[tid * TPT + q];
        if ((p & 15) == e || (p >> 4) == e) ++n;
    }
    cnt[tid] = n;
    __syncthreads();
#pragma unroll
    for (int off = 1; off < 256; off <<= 1) {
        int v = (tid >= off) ? cnt[tid - off] : 0;
        __syncthreads();
        cnt[tid] += v;
        __syncthreads();
    }
    int base = cnt[tid] - n;
    if (tid == 255) counts[e] = cnt[255];
    int* dst = lists + e * T_TOK;
#pragma unroll
    for (int q = 0; q < TPT; ++q) {
        int t = tid * TPT + q;
        int p = pairs[t];
        if ((p & 15) == e)      dst[base++] = 2 * t;
        else if ((p >> 4) == e) dst[base++] = 2 * t + 1;
    }
}

// GEMM1: h[slot] = silu(x@Wg)*(x@Wu). 128x128 tile, BK=32, dbuf with counted
// vmcnt: stage(k+1) -> vmcnt(6)+barrier -> compute(k) -> barrier.
// Block mapping: expert = bid&7 (one XCD per expert), mt fastest.
__global__ __launch_bounds__(256, 2) void gemm1_kernel(
    const bf16_t* __restrict__ xbf, const bf16_t* __restrict__ wgT,
    const bf16_t* __restrict__ wuT, const int* __restrict__ lists,
    const int* __restrict__ counts, bf16_t* __restrict__ h)
{
    const int MT = T_TOK / 128;  // 32
    int bid = blockIdx.x;
    int e = bid & 7;
    int within = bid >> 3;       // 0..351
    int nt = within / MT;        // 0..10
    int mt = within - nt * MT;   // mt fastest: A rows of expert stay in L2
    int cnt = counts[e];
    int mbase = mt * 128;
    if (mbase >= cnt) return;
    int rows = min(128, cnt - mbase);

    __shared__ __align__(16) bf16_t As[2][128 * 32];
    __shared__ __align__(16) bf16_t Bg[2][128 * 32];
    __shared__ __align__(16) bf16_t Bu[2][128 * 32];
    __shared__ int slots[128];

    int tid = threadIdx.x;
    if (tid < 128) slots[tid] = (tid < rows) ? lists[e * T_TOK + mbase + tid] : 0;
    __syncthreads();

    int r0 = tid >> 2;
    int c0 = (tid & 3) * 8;
    const bf16_t* gA0 = xbf + (size_t)(slots[r0] >> 1) * D_DIM + c0;
    const bf16_t* gA1 = xbf + (size_t)(slots[64 + r0] >> 1) * D_DIM + c0;
    const bf16_t* gB0 = wgT + ((size_t)e * H_DIM + nt * 128 + r0) * D_DIM + c0;
    const bf16_t* gB1 = gB0 + (size_t)64 * D_DIM;
    const bf16_t* gU0 = wuT + ((size_t)e * H_DIM + nt * 128 + r0) * D_DIM + c0;
    const bf16_t* gU1 = gU0 + (size_t)64 * D_DIM;

    int wid = tid >> 6, lane = tid & 63;
    int wm = (wid >> 1) * 64, wn = (wid & 1) * 64;
    int lr = lane & 15, lq = lane >> 4;

    f32x4 accg[4][4], accu[4][4];
#pragma unroll
    for (int i = 0; i < 4; ++i)
#pragma unroll
        for (int j = 0; j < 4; ++j) {
            accg[i][j] = (f32x4){0.f, 0.f, 0.f, 0.f};
            accu[i][j] = (f32x4){0.f, 0.f, 0.f, 0.f};
        }

    // prologue: stage k-tile 0 into buffer 0 (6 loads in flight)
    {
        bf16_t* lA = As[0] + tid * 8;
        bf16_t* lG = Bg[0] + tid * 8;
        bf16_t* lU = Bu[0] + tid * 8;
        gload16(gA0, lA); gload16(gA1, lA + 2048);
        gload16(gB0, lG); gload16(gB1, lG + 2048);
        gload16(gU0, lU); gload16(gU1, lU + 2048);
    }

    const int NK = D_DIM / 32;
    int cur = 0;
    for (int kt = 0; kt < NK; ++kt) {
        if (kt + 1 < NK) {
            // issue next k-tile (6 loads) -> 12 outstanding
            int nxt = cur ^ 1;
            int ko = (kt + 1) * 32;
            bf16_t* lA = As[nxt] + tid * 8;
            bf16_t* lG = Bg[nxt] + tid * 8;
            bf16_t* lU = Bu[nxt] + tid * 8;
            gload16(gA0 + ko, lA); gload16(gA1 + ko, lA + 2048);
            gload16(gB0 + ko, lG); gload16(gB1 + ko, lG + 2048);
            gload16(gU0 + ko, lU); gload16(gU1 + ko, lU + 2048);
            // wait only the 6 oldest (tile k); next tile stays in flight
            asm volatile("s_waitcnt vmcnt(6)" ::: "memory");
        } else {
            asm volatile("s_waitcnt vmcnt(0)" ::: "memory");
        }
        __builtin_amdgcn_s_barrier();           // all waves' tile-k loads landed
        __builtin_amdgcn_sched_barrier(0);
        // compute CURRENT buffer
        bf16x8 af[4], bg[4], bu[4];
#pragma unroll
        for (int i = 0; i < 4; ++i)
            af[i] = *(const bf16x8*)(As[cur] + (wm + i * 16 + lr) * 32 + lq * 8);
#pragma unroll
        for (int j = 0; j < 4; ++j) {
            bg[j] = *(const bf16x8*)(Bg[cur] + (wn + j * 16 + lr) * 32 + lq * 8);
            bu[j] = *(const bf16x8*)(Bu[cur] + (wn + j * 16 + lr) * 32 + lq * 8);
        }
#pragma unroll
        for (int i = 0; i < 4; ++i)
#pragma unroll
            for (int j = 0; j < 4; ++j) {
                accg[i][j] = __builtin_amdgcn_mfma_f32_16x16x32_bf16(af[i], bg[j], accg[i][j], 0, 0, 0);
                accu[i][j] = __builtin_amdgcn_mfma_f32_16x16x32_bf16(af[i], bu[j], accu[i][j], 0, 0, 0);
            }
        // protect buffer reuse: next window stages into the buffer just read
        __builtin_amdgcn_s_barrier();
        cur ^= 1;
    }

#pragma unroll
    for (int i = 0; i < 4; ++i) {
#pragma unroll
        for (int jj = 0; jj < 4; ++jj) {
            int row = wm + i * 16 + lq * 4 + jj;
            if (row < rows) {
                int slot = slots[row];
                bf16_t* hrow = h + (size_t)slot * H_DIM + (size_t)nt * 128 + wn;
#pragma unroll
                for (int j = 0; j < 4; ++j) {
                    float g = accg[i][j][jj];
                    float u = accu[i][j][jj];
                    float val = (g / (1.f + __expf(-g))) * u;
                    hrow[j * 16 + lr] = (bf16_t)val;
                }
            }
        }
    }
}

// GEMM2: contrib[slot] = (h[slot] @ Wd[e]) * comb_weight. Counted vmcnt(4).
__global__ __launch_bounds__(256, 2) void gemm2_kernel(
    const bf16_t* __restrict__ h, const bf16_t* __restrict__ wdT,
    const int* __restrict__ lists, const int* __restrict__ counts,
    const float* __restrict__ comb, bf16_t* __restrict__ contrib)
{
    const int MT = T_TOK / 128;  // 32
    int bid = blockIdx.x;
    int e = bid & 7;
    int within = bid >> 3;       // 0..255
    int nt = within / MT;        // 0..7
    int mt = within - nt * MT;
    int cnt = counts[e];
    int mbase = mt * 128;
    if (mbase >= cnt) return;
    int rows = min(128, cnt - mbase);

    __shared__ __align__(16) bf16_t As[2][128 * 32];
    __shared__ __align__(16) bf16_t Bs[2][128 * 32];
    __shared__ int slots[128];

    int tid = threadIdx.x;
    if (tid < 128) slots[tid] = (tid < rows) ? lists[e * T_TOK + mbase + tid] : 0;
    __syncthreads();

    int r0 = tid >> 2;
    int c0 = (tid & 3) * 8;
    const bf16_t* gA0 = h + (size_t)slots[r0] * H_DIM + c0;
    const bf16_t* gA1 = h + (size_t)slots[64 + r0] * H_DIM + c0;
    const bf16_t* gB0 = wdT + ((size_t)e * D_DIM + nt * 128 + r0) * H_DIM + c0;
    const bf16_t* gB1 = gB0 + (size_t)64 * H_DIM;

    int wid = tid >> 6, lane = tid & 63;
    int wm = (wid >> 1) * 64, wn = (wid & 1) * 64;
    int lr = lane & 15, lq = lane >> 4;

    f32x4 acc[4][4];
#pragma unroll
    for (int i = 0; i < 4; ++i)
#pragma unroll
        for (int j = 0; j < 4; ++j) acc[i][j] = (f32x4){0.f, 0.f, 0.f, 0.f};

    {
        bf16_t* lA = As[0] + tid * 8;
        bf16_t* lB = Bs[0] + tid * 8;
        gload16(gA0, lA); gload16(gA1, lA + 2048);
        gload16(gB0, lB); gload16(gB1, lB + 2048);
    }

    const int NK = H_DIM / 32;
    int cur = 0;
    for (int kt = 0; kt < NK; ++kt) {
        if (kt + 1 < NK) {
            int nxt = cur ^ 1;
            int ko = (kt + 1) * 32;
            bf16_t* lA = As[nxt] + tid * 8;
            bf16_t* lB = Bs[nxt] + tid * 8;
            gload16(gA0 + ko, lA); gload16(gA1 + ko, lA + 2048);
            gload16(gB0 + ko, lB); gload16(gB1 + ko, lB + 2048);
            asm volatile("s_waitcnt vmcnt(4)" ::: "memory");
        } else {
            asm volatile("s_waitcnt vmcnt(0)" ::: "memory");
        }
        __builtin_amdgcn_s_barrier();
        __builtin_amdgcn_sched_barrier(0);
        bf16x8 af[4], bf[4];
#pragma unroll
        for (int i = 0; i < 4; ++i)
            af[i] = *(const bf16x8*)(As[cur] + (wm + i * 16 + lr) * 32 + lq * 8);
#pragma unroll
        for (int j = 0; j < 4; ++j)
            bf[j] = *(const bf16x8*)(Bs[cur] + (wn + j * 16 + lr) * 32 + lq * 8);
#pragma unroll
        for (int i = 0; i < 4; ++i)
#pragma unroll
            for (int j = 0; j < 4; ++j)
                acc[i][j] = __builtin_amdgcn_mfma_f32_16x16x32_bf16(af[i], bf[j], acc[i][j], 0, 0, 0);
        __builtin_amdgcn_s_barrier();
        cur ^= 1;
    }

#pragma unroll
    for (int i = 0; i < 4; ++i) {
#pragma unroll
        for (int jj = 0; jj < 4; ++jj) {
            int row = wm + i * 16 + lq * 4 + jj;
            if (row < rows) {
                int slot = slots[row];
                float wgt = comb[(slot >> 1) * E_NUM + e];
                bf16_t* crow = contrib + (size_t)slot * D_DIM + (size_t)nt * 128 + wn;
#pragma unroll
                for (int j = 0; j < 4; ++j)
                    crow[j * 16 + lr] = (bf16_t)(acc[i][j][jj] * wgt);
            }
        }
    }
}

// out[t][d] = contrib[2t][d] + contrib[2t+1][d]
__global__ __launch_bounds__(256) void combine_kernel(
    const bf16_t* __restrict__ contrib, float* __restrict__ out)
{
    int idx = blockIdx.x * 256 + threadIdx.x;
    int t = idx >> 7;
    int d = (idx & 127) * 8;
    bf16x8 a = *(const bf16x8*)(contrib + (size_t)(2 * t) * D_DIM + d);
    bf16x8 b = *(const bf16x8*)(contrib + (size_t)(2 * t + 1) * D_DIM + d);
    float4 r0, r1;
    r0.x = (float)a[0] + (float)b[0];
    r0.y = (float)a[1] + (float)b[1];
    r0.z = (float)a[2] + (float)b[2];
    r0.w = (float)a[3] + (float)b[3];
    r1.x = (float)a[4] + (float)b[4];
    r1.y = (float)a[5] + (float)b[5];
    r1.z = (float)a[6] + (float)b[6];
    r1.w = (float)a[7] + (float)b[7];
    *(float4*)(out + (size_t)t * D_DIM + d) = r0;
    *(float4*)(out + (size_t)t * D_DIM + d + 4) = r1;
}

extern "C" void kernel_launch(void* const* d_in, const int* in_sizes, int n_in,
                              void* d_out, int out_size, void* d_ws, size_t ws_size,
                              hipStream_t stream)
{
    const float* x  = (const float*)d_in[0];
    const float* wr = (const float*)d_in[1];
    const float* wg = (const float*)d_in[2];
    const float* wu = (const float*)d_in[3];
    const float* wd = (const float*)d_in[4];
    float* out = (float*)d_out;

    char* ws = (char*)d_ws;
    int*    counts  = (int*)(ws + OFF_COUNTS);
    float*  comb    = (float*)(ws + OFF_COMB);
    int*    lists   = (int*)(ws + OFF_LISTS);
    unsigned char* pairs = (unsigned char*)(ws + OFF_PAIRS);
    bf16_t* xbf     = (bf16_t*)(ws + OFF_XBF);
    bf16_t* wgT     = (bf16_t*)(ws + OFF_WGT);
    bf16_t* wuT     = (bf16_t*)(ws + OFF_WUT);
    bf16_t* wdT     = (bf16_t*)(ws + OFF_WDT);
    bf16_t* h       = (bf16_t*)(ws + OFF_H);
    bf16_t* contrib = (bf16_t*)(ws + OFF_CONTRIB);

    // wg, wu: [E][D][H] -> [E][H][D] bf16
    transpose_cvt_kernel<<<dim3(H_DIM / 64, D_DIM / 64, E_NUM), dim3(256), 0, stream>>>(
        wg, wgT, D_DIM, H_DIM);
    transpose_cvt_kernel<<<dim3(H_DIM / 64, D_DIM / 64, E_NUM), dim3(256), 0, stream>>>(
        wu, wuT, D_DIM, H_DIM);
    // wd: [E][H][D] -> [E][D][H] bf16
    transpose_cvt_kernel<<<dim3(D_DIM / 64, H_DIM / 64, E_NUM), dim3(256), 0, stream>>>(
        wd, wdT, H_DIM, D_DIM);
    router_score_kernel<<<dim3(T_TOK / 4), dim3(256), 0, stream>>>(
        x, wr, xbf, comb, pairs);
    build_lists_kernel<<<dim3(E_NUM), dim3(256), 0, stream>>>(pairs, lists, counts);
    gemm1_kernel<<<dim3(E_NUM * (T_TOK / 128) * (H_DIM / 128)), dim3(256), 0, stream>>>(
        xbf, wgT, wuT, lists, counts, h);
    gemm2_kernel<<<dim3(E_NUM * (T_TOK / 128) * (D_DIM / 128)), dim3(256), 0, stream>>>(
        h, wdT, lists, counts, comb, contrib);
    combine_kernel<<<dim3(T_TOK * D_DIM / 8 / 256), dim3(256), 0, stream>>>(contrib, out);
}

// Round 6
// 202.936 us; speedup vs baseline: 1.1473x; 1.0208x over previous
//
#include <hip/hip_runtime.h>
#include <hip/hip_bf16.h>

// MoE FFN: T=4096 tokens, D=1024, E=8, H=1408, top-2.
// R6: GEMM pipelines deepened to 2 tiles in flight (3-buffer rotation).
// stage(k+2) -> vmcnt(12|8) [tile k landed, k+1/k+2 in flight] -> barrier ->
// compute(k) -> barrier. Covers ~900cyc HBM latency with two compute windows.
// XCD expert mapping + mt-fastest kept (FETCH is at compulsory minimum).

#define T_TOK 4096
#define D_DIM 1024
#define E_NUM 8
#define H_DIM 1408

typedef __bf16 bf16_t;
typedef __bf16 bf16x8 __attribute__((ext_vector_type(8)));
typedef float f32x4 __attribute__((ext_vector_type(4)));

// ---- workspace layout (bytes) ----
#define OFF_COUNTS   0
#define OFF_COMB     256                                   // T*E*4 = 131072
#define OFF_LISTS    (OFF_COMB + T_TOK*E_NUM*4)            // E*T*4 = 131072
#define OFF_PAIRS    (OFF_LISTS + E_NUM*T_TOK*4)           // T bytes
#define OFF_XBF      (OFF_PAIRS + T_TOK)                   // T*D*2
#define OFF_WGT      (OFF_XBF + (size_t)T_TOK*D_DIM*2)     // E*H*D*2 each
#define OFF_WUT      (OFF_WGT + (size_t)E_NUM*H_DIM*D_DIM*2)
#define OFF_WDT      (OFF_WUT + (size_t)E_NUM*H_DIM*D_DIM*2)
#define OFF_H        (OFF_WDT + (size_t)E_NUM*H_DIM*D_DIM*2)
#define OFF_CONTRIB  (OFF_H + (size_t)2*T_TOK*H_DIM*2)
// total ~117.7 MB

__device__ __forceinline__ void gload16(const bf16_t* g, bf16_t* l) {
    __builtin_amdgcn_global_load_lds(
        (const __attribute__((address_space(1))) void*)g,
        (__attribute__((address_space(3))) void*)l,
        16, 0, 0);
}

// Tiled transpose+convert: per expert, in [R][C] fp32 -> out [C][R] bf16.
__global__ __launch_bounds__(256) void transpose_cvt_kernel(
    const float* __restrict__ in, bf16_t* __restrict__ out, int R, int C)
{
    int e = blockIdx.z;
    int rt = blockIdx.y, ct = blockIdx.x;
    __shared__ bf16_t tile[64][65];
    int tid = threadIdx.x;
    int r = tid >> 2, c0 = (tid & 3) * 16;
    const float* src = in + ((size_t)e * R + rt * 64) * C + (size_t)ct * 64;
#pragma unroll
    for (int q = 0; q < 4; ++q) {
        float4 f = *(const float4*)(src + (size_t)r * C + c0 + q * 4);
        tile[c0 + q * 4 + 0][r] = (bf16_t)f.x;
        tile[c0 + q * 4 + 1][r] = (bf16_t)f.y;
        tile[c0 + q * 4 + 2][r] = (bf16_t)f.z;
        tile[c0 + q * 4 + 3][r] = (bf16_t)f.w;
    }
    __syncthreads();
    bf16_t* dst = out + ((size_t)e * C + ct * 64) * R + (size_t)rt * 64;
    int cc = tid >> 2, rr0 = (tid & 3) * 16;
    bf16x8 v0, v1;
#pragma unroll
    for (int q = 0; q < 8; ++q) { v0[q] = tile[cc][rr0 + q]; v1[q] = tile[cc][rr0 + 8 + q]; }
    *(bf16x8*)(dst + (size_t)cc * R + rr0) = v0;
    *(bf16x8*)(dst + (size_t)cc * R + rr0 + 8) = v1;
}

// Router phase A: 4 waves/block, one token per wave. No atomics. x -> bf16.
__global__ __launch_bounds__(256) void router_score_kernel(
    const float* __restrict__ x, const float* __restrict__ wr,
    bf16_t* __restrict__ xbf, float* __restrict__ comb,
    unsigned char* __restrict__ pairs)
{
    int widx = threadIdx.x >> 6;
    int lane = threadIdx.x & 63;
    int t = blockIdx.x * 4 + widx;
    const float* xr = x + (size_t)t * D_DIM;

    {
        const float4* xv4 = (const float4*)(xr + lane * 16);
        bf16_t* xbr = xbf + (size_t)t * D_DIM + lane * 16;
        float4 f0 = xv4[0], f1 = xv4[1], f2 = xv4[2], f3 = xv4[3];
        bf16x8 v0, v1;
        v0[0] = (bf16_t)f0.x; v0[1] = (bf16_t)f0.y; v0[2] = (bf16_t)f0.z; v0[3] = (bf16_t)f0.w;
        v0[4] = (bf16_t)f1.x; v0[5] = (bf16_t)f1.y; v0[6] = (bf16_t)f1.z; v0[7] = (bf16_t)f1.w;
        v1[0] = (bf16_t)f2.x; v1[1] = (bf16_t)f2.y; v1[2] = (bf16_t)f2.z; v1[3] = (bf16_t)f2.w;
        v1[4] = (bf16_t)f3.x; v1[5] = (bf16_t)f3.y; v1[6] = (bf16_t)f3.z; v1[7] = (bf16_t)f3.w;
        *(bf16x8*)(xbr) = v0;
        *(bf16x8*)(xbr + 8) = v1;
    }

    float acc[E_NUM] = {0.f, 0.f, 0.f, 0.f, 0.f, 0.f, 0.f, 0.f};
#pragma unroll
    for (int j = 0; j < D_DIM / 64; ++j) {
        float xv = xr[lane + 64 * j];
        const float* w = wr + (size_t)(lane + 64 * j) * E_NUM;
#pragma unroll
        for (int e = 0; e < E_NUM; ++e) acc[e] += xv * w[e];
    }
#pragma unroll
    for (int off = 32; off > 0; off >>= 1) {
#pragma unroll
        for (int e = 0; e < E_NUM; ++e) acc[e] += __shfl_xor(acc[e], off, 64);
    }
    if (lane == 0) {
        float m = acc[0];
#pragma unroll
        for (int e = 1; e < E_NUM; ++e) m = fmaxf(m, acc[e]);
        float ex[E_NUM], Z = 0.f;
#pragma unroll
        for (int e = 0; e < E_NUM; ++e) { ex[e] = expf(acc[e] - m); Z += ex[e]; }
        float inv = 1.f / Z;
        int e0 = 0; float v0 = ex[0];
#pragma unroll
        for (int e = 1; e < E_NUM; ++e) if (ex[e] > v0) { v0 = ex[e]; e0 = e; }
        int e1 = -1; float v1 = -1.f;
#pragma unroll
        for (int e = 0; e < E_NUM; ++e) if (e != e0 && ex[e] > v1) { v1 = ex[e]; e1 = e; }
        float p0 = v0 * inv, p1 = v1 * inv;
        float s = p0 + p1 + 1e-20f;
        comb[t * E_NUM + e0] = p0 / s;
        comb[t * E_NUM + e1] = p1 / s;
        pairs[t] = (unsigned char)(e0 | (e1 << 4));
    }
}

// Router phase B: one block per expert, LDS-scan compaction. Deterministic.
__global__ __launch_bounds__(256) void build_lists_kernel(
    const unsigned char* __restrict__ pairs, int* __restrict__ lists,
    int* __restrict__ counts)
{
    int e = blockIdx.x;
    int tid = threadIdx.x;
    __shared__ int cnt[256];

    const int TPT = T_TOK / 256;
    int n = 0;
#pragma unroll
    for (int q = 0; q < TPT; ++q) {
        int p = pairs[tid * TPT + q];
        if ((p & 15) == e || (p >> 4) == e) ++n;
    }
    cnt[tid] = n;
    __syncthreads();
#pragma unroll
    for (int off = 1; off < 256; off <<= 1) {
        int v = (tid >= off) ? cnt[tid - off] : 0;
        __syncthreads();
        cnt[tid] += v;
        __syncthreads();
    }
    int base = cnt[tid] - n;
    if (tid == 255) counts[e] = cnt[255];
    int* dst = lists + e * T_TOK;
#pragma unroll
    for (int q = 0; q < TPT; ++q) {
        int t = tid * TPT + q;
        int p = pairs[t];
        if ((p & 15) == e)      dst[base++] = 2 * t;
        else if ((p >> 4) == e) dst[base++] = 2 * t + 1;
    }
}

// GEMM1: h[slot] = silu(x@Wg)*(x@Wu). 128x128 tile, BK=32, 3-buffer rotation,
// 2 tiles in flight: stage(k+2) -> vmcnt(12) -> barrier -> compute(k) -> barrier.
__global__ __launch_bounds__(256, 2) void gemm1_kernel(
    const bf16_t* __restrict__ xbf, const bf16_t* __restrict__ wgT,
    const bf16_t* __restrict__ wuT, const int* __restrict__ lists,
    const int* __restrict__ counts, bf16_t* __restrict__ h)
{
    const int MT = T_TOK / 128;  // 32
    int bid = blockIdx.x;
    int e = bid & 7;
    int within = bid >> 3;       // 0..351
    int nt = within / MT;        // 0..10
    int mt = within - nt * MT;   // mt fastest: A rows of expert stay in L2
    int cnt = counts[e];
    int mbase = mt * 128;
    if (mbase >= cnt) return;
    int rows = min(128, cnt - mbase);

    __shared__ __align__(16) bf16_t As[3][128 * 32];
    __shared__ __align__(16) bf16_t Bg[3][128 * 32];
    __shared__ __align__(16) bf16_t Bu[3][128 * 32];
    __shared__ int slots[128];

    int tid = threadIdx.x;
    if (tid < 128) slots[tid] = (tid < rows) ? lists[e * T_TOK + mbase + tid] : 0;
    __syncthreads();

    int r0 = tid >> 2;
    int c0 = (tid & 3) * 8;
    const bf16_t* gA0 = xbf + (size_t)(slots[r0] >> 1) * D_DIM + c0;
    const bf16_t* gA1 = xbf + (size_t)(slots[64 + r0] >> 1) * D_DIM + c0;
    const bf16_t* gB0 = wgT + ((size_t)e * H_DIM + nt * 128 + r0) * D_DIM + c0;
    const bf16_t* gB1 = gB0 + (size_t)64 * D_DIM;
    const bf16_t* gU0 = wuT + ((size_t)e * H_DIM + nt * 128 + r0) * D_DIM + c0;
    const bf16_t* gU1 = gU0 + (size_t)64 * D_DIM;

    int wid = tid >> 6, lane = tid & 63;
    int wm = (wid >> 1) * 64, wn = (wid & 1) * 64;
    int lr = lane & 15, lq = lane >> 4;

    f32x4 accg[4][4], accu[4][4];
#pragma unroll
    for (int i = 0; i < 4; ++i)
#pragma unroll
        for (int j = 0; j < 4; ++j) {
            accg[i][j] = (f32x4){0.f, 0.f, 0.f, 0.f};
            accu[i][j] = (f32x4){0.f, 0.f, 0.f, 0.f};
        }

    const int NK = D_DIM / 32;  // 32
    // prologue: stage tiles 0,1 into bufs 0,1 (12 loads in flight)
#pragma unroll
    for (int p = 0; p < 2; ++p) {
        bf16_t* lA = As[p] + tid * 8;
        bf16_t* lG = Bg[p] + tid * 8;
        bf16_t* lU = Bu[p] + tid * 8;
        int ko = p * 32;
        gload16(gA0 + ko, lA); gload16(gA1 + ko, lA + 2048);
        gload16(gB0 + ko, lG); gload16(gB1 + ko, lG + 2048);
        gload16(gU0 + ko, lU); gload16(gU1 + ko, lU + 2048);
    }

    int cur = 0, nxt2 = 2;   // buffer indices mod 3
    for (int kt = 0; kt < NK; ++kt) {
        if (kt + 2 < NK) {
            // issue tile k+2 (6 loads) -> up to 18 outstanding
            int ko = (kt + 2) * 32;
            bf16_t* lA = As[nxt2] + tid * 8;
            bf16_t* lG = Bg[nxt2] + tid * 8;
            bf16_t* lU = Bu[nxt2] + tid * 8;
            gload16(gA0 + ko, lA); gload16(gA1 + ko, lA + 2048);
            gload16(gB0 + ko, lG); gload16(gB1 + ko, lG + 2048);
            gload16(gU0 + ko, lU); gload16(gU1 + ko, lU + 2048);
            // wait until only k+1,k+2 in flight => tile k landed
            asm volatile("s_waitcnt vmcnt(12)" ::: "memory");
        } else if (kt + 1 < NK) {
            asm volatile("s_waitcnt vmcnt(6)" ::: "memory");
        } else {
            asm volatile("s_waitcnt vmcnt(0)" ::: "memory");
        }
        __builtin_amdgcn_s_barrier();           // tile-k data visible to all waves
        __builtin_amdgcn_sched_barrier(0);
        // compute buffer cur (= tile k)
        bf16x8 af[4], bg[4], bu[4];
#pragma unroll
        for (int i = 0; i < 4; ++i)
            af[i] = *(const bf16x8*)(As[cur] + (wm + i * 16 + lr) * 32 + lq * 8);
#pragma unroll
        for (int j = 0; j < 4; ++j) {
            bg[j] = *(const bf16x8*)(Bg[cur] + (wn + j * 16 + lr) * 32 + lq * 8);
            bu[j] = *(const bf16x8*)(Bu[cur] + (wn + j * 16 + lr) * 32 + lq * 8);
        }
#pragma unroll
        for (int i = 0; i < 4; ++i)
#pragma unroll
            for (int j = 0; j < 4; ++j) {
                accg[i][j] = __builtin_amdgcn_mfma_f32_16x16x32_bf16(af[i], bg[j], accg[i][j], 0, 0, 0);
                accu[i][j] = __builtin_amdgcn_mfma_f32_16x16x32_bf16(af[i], bu[j], accu[i][j], 0, 0, 0);
            }
        // protect buffer reuse (buf cur is restaged at iter k+1)
        __builtin_amdgcn_s_barrier();
        cur = (cur == 2) ? 0 : cur + 1;
        nxt2 = (nxt2 == 2) ? 0 : nxt2 + 1;
    }

#pragma unroll
    for (int i = 0; i < 4; ++i) {
#pragma unroll
        for (int jj = 0; jj < 4; ++jj) {
            int row = wm + i * 16 + lq * 4 + jj;
            if (row < rows) {
                int slot = slots[row];
                bf16_t* hrow = h + (size_t)slot * H_DIM + (size_t)nt * 128 + wn;
#pragma unroll
                for (int j = 0; j < 4; ++j) {
                    float g = accg[i][j][jj];
                    float u = accu[i][j][jj];
                    float val = (g / (1.f + __expf(-g))) * u;
                    hrow[j * 16 + lr] = (bf16_t)val;
                }
            }
        }
    }
}

// GEMM2: contrib[slot] = (h[slot] @ Wd[e]) * comb_weight. 3-buf, vmcnt(8).
__global__ __launch_bounds__(256, 3) void gemm2_kernel(
    const bf16_t* __restrict__ h, const bf16_t* __restrict__ wdT,
    const int* __restrict__ lists, const int* __restrict__ counts,
    const float* __restrict__ comb, bf16_t* __restrict__ contrib)
{
    const int MT = T_TOK / 128;  // 32
    int bid = blockIdx.x;
    int e = bid & 7;
    int within = bid >> 3;       // 0..255
    int nt = within / MT;        // 0..7
    int mt = within - nt * MT;
    int cnt = counts[e];
    int mbase = mt * 128;
    if (mbase >= cnt) return;
    int rows = min(128, cnt - mbase);

    __shared__ __align__(16) bf16_t As[3][128 * 32];
    __shared__ __align__(16) bf16_t Bs[3][128 * 32];
    __shared__ int slots[128];

    int tid = threadIdx.x;
    if (tid < 128) slots[tid] = (tid < rows) ? lists[e * T_TOK + mbase + tid] : 0;
    __syncthreads();

    int r0 = tid >> 2;
    int c0 = (tid & 3) * 8;
    const bf16_t* gA0 = h + (size_t)slots[r0] * H_DIM + c0;
    const bf16_t* gA1 = h + (size_t)slots[64 + r0] * H_DIM + c0;
    const bf16_t* gB0 = wdT + ((size_t)e * D_DIM + nt * 128 + r0) * H_DIM + c0;
    const bf16_t* gB1 = gB0 + (size_t)64 * H_DIM;

    int wid = tid >> 6, lane = tid & 63;
    int wm = (wid >> 1) * 64, wn = (wid & 1) * 64;
    int lr = lane & 15, lq = lane >> 4;

    f32x4 acc[4][4];
#pragma unroll
    for (int i = 0; i < 4; ++i)
#pragma unroll
        for (int j = 0; j < 4; ++j) acc[i][j] = (f32x4){0.f, 0.f, 0.f, 0.f};

    const int NK = H_DIM / 32;  // 44
#pragma unroll
    for (int p = 0; p < 2; ++p) {
        bf16_t* lA = As[p] + tid * 8;
        bf16_t* lB = Bs[p] + tid * 8;
        int ko = p * 32;
        gload16(gA0 + ko, lA); gload16(gA1 + ko, lA + 2048);
        gload16(gB0 + ko, lB); gload16(gB1 + ko, lB + 2048);
    }

    int cur = 0, nxt2 = 2;
    for (int kt = 0; kt < NK; ++kt) {
        if (kt + 2 < NK) {
            int ko = (kt + 2) * 32;
            bf16_t* lA = As[nxt2] + tid * 8;
            bf16_t* lB = Bs[nxt2] + tid * 8;
            gload16(gA0 + ko, lA); gload16(gA1 + ko, lA + 2048);
            gload16(gB0 + ko, lB); gload16(gB1 + ko, lB + 2048);
            asm volatile("s_waitcnt vmcnt(8)" ::: "memory");
        } else if (kt + 1 < NK) {
            asm volatile("s_waitcnt vmcnt(4)" ::: "memory");
        } else {
            asm volatile("s_waitcnt vmcnt(0)" ::: "memory");
        }
        __builtin_amdgcn_s_barrier();
        __builtin_amdgcn_sched_barrier(0);
        bf16x8 af[4], bf[4];
#pragma unroll
        for (int i = 0; i < 4; ++i)
            af[i] = *(const bf16x8*)(As[cur] + (wm + i * 16 + lr) * 32 + lq * 8);
#pragma unroll
        for (int j = 0; j < 4; ++j)
            bf[j] = *(const bf16x8*)(Bs[cur] + (wn + j * 16 + lr) * 32 + lq * 8);
#pragma unroll
        for (int i = 0; i < 4; ++i)
#pragma unroll
            for (int j = 0; j < 4; ++j)
                acc[i][j] = __builtin_amdgcn_mfma_f32_16x16x32_bf16(af[i], bf[j], acc[i][j], 0, 0, 0);
        __builtin_amdgcn_s_barrier();
        cur = (cur == 2) ? 0 : cur + 1;
        nxt2 = (nxt2 == 2) ? 0 : nxt2 + 1;
    }

#pragma unroll
    for (int i = 0; i < 4; ++i) {
#pragma unroll
        for (int jj = 0; jj < 4; ++jj) {
            int row = wm + i * 16 + lq * 4 + jj;
            if (row < rows) {
                int slot = slots[row];
                float wgt = comb[(slot >> 1) * E_NUM + e];
                bf16_t* crow = contrib + (size_t)slot * D_DIM + (size_t)nt * 128 + wn;
#pragma unroll
                for (int j = 0; j < 4; ++j)
                    crow[j * 16 + lr] = (bf16_t)(acc[i][j][jj] * wgt);
            }
        }
    }
}

// out[t][d] = contrib[2t][d] + contrib[2t+1][d]
__global__ __launch_bounds__(256) void combine_kernel(
    const bf16_t* __restrict__ contrib, float* __restrict__ out)
{
    int idx = blockIdx.x * 256 + threadIdx.x;
    int t = idx >> 7;
    int d = (idx & 127) * 8;
    bf16x8 a = *(const bf16x8*)(contrib + (size_t)(2 * t) * D_DIM + d);
    bf16x8 b = *(const bf16x8*)(contrib + (size_t)(2 * t + 1) * D_DIM + d);
    float4 r0, r1;
    r0.x = (float)a[0] + (float)b[0];
    r0.y = (float)a[1] + (float)b[1];
    r0.z = (float)a[2] + (float)b[2];
    r0.w = (float)a[3] + (float)b[3];
    r1.x = (float)a[4] + (float)b[4];
    r1.y = (float)a[5] + (float)b[5];
    r1.z = (float)a[6] + (float)b[6];
    r1.w = (float)a[7] + (float)b[7];
    *(float4*)(out + (size_t)t * D_DIM + d) = r0;
    *(float4*)(out + (size_t)t * D_DIM + d + 4) = r1;
}

extern "C" void kernel_launch(void* const* d_in, const int* in_sizes, int n_in,
                              void* d_out, int out_size, void* d_ws, size_t ws_size,
                              hipStream_t stream)
{
    const float* x  = (const float*)d_in[0];
    const float* wr = (const float*)d_in[1];
    const float* wg = (const float*)d_in[2];
    const float* wu = (const float*)d_in[3];
    const float* wd = (const float*)d_in[4];
    float* out = (float*)d_out;

    char* ws = (char*)d_ws;
    int*    counts  = (int*)(ws + OFF_COUNTS);
    float*  comb    = (float*)(ws + OFF_COMB);
    int*    lists   = (int*)(ws + OFF_LISTS);
    unsigned char* pairs = (unsigned char*)(ws + OFF_PAIRS);
    bf16_t* xbf     = (bf16_t*)(ws + OFF_XBF);
    bf16_t* wgT     = (bf16_t*)(ws + OFF_WGT);
    bf16_t* wuT     = (bf16_t*)(ws + OFF_WUT);
    bf16_t* wdT     = (bf16_t*)(ws + OFF_WDT);
    bf16_t* h       = (bf16_t*)(ws + OFF_H);
    bf16_t* contrib = (bf16_t*)(ws + OFF_CONTRIB);

    // wg, wu: [E][D][H] -> [E][H][D] bf16
    transpose_cvt_kernel<<<dim3(H_DIM / 64, D_DIM / 64, E_NUM), dim3(256), 0, stream>>>(
        wg, wgT, D_DIM, H_DIM);
    transpose_cvt_kernel<<<dim3(H_DIM / 64, D_DIM / 64, E_NUM), dim3(256), 0, stream>>>(
        wu, wuT, D_DIM, H_DIM);
    // wd: [E][H][D] -> [E][D][H] bf16
    transpose_cvt_kernel<<<dim3(D_DIM / 64, H_DIM / 64, E_NUM), dim3(256), 0, stream>>>(
        wd, wdT, H_DIM, D_DIM);
    router_score_kernel<<<dim3(T_TOK / 4), dim3(256), 0, stream>>>(
        x, wr, xbf, comb, pairs);
    build_lists_kernel<<<dim3(E_NUM), dim3(256), 0, stream>>>(pairs, lists, counts);
    gemm1_kernel<<<dim3(E_NUM * (T_TOK / 128) * (H_DIM / 128)), dim3(256), 0, stream>>>(
        xbf, wgT, wuT, lists, counts, h);
    gemm2_kernel<<<dim3(E_NUM * (T_TOK / 128) * (D_DIM / 128)), dim3(256), 0, stream>>>(
        h, wdT, lists, counts, comb, contrib);
    combine_kernel<<<dim3(T_TOK * D_DIM / 8 / 256), dim3(256), 0, stream>>>(contrib, out);
}